// Round 1
// baseline (345.620 us; speedup 1.0000x reference)
//
#include <hip/hip_runtime.h>
#include <cstdint>
#include <cstddef>

#define NCH 128
#define GR 32

__device__ __forceinline__ int load_ei(const void* p, long long i, int is64) {
  return is64 ? (int)((const long long*)p)[i] : ((const int*)p)[i];
}

// Detect whether edge_index is int64 (odd 32-bit words all zero) or int32.
__global__ void k_detect(const unsigned int* __restrict__ ei, int* __restrict__ flag) {
  int t = threadIdx.x;  // 0..63
  unsigned int v = ei[2 * t + 1];
  unsigned long long b = __ballot(v != 0u);
  if (t == 0) *flag = (b == 0ULL) ? 1 : 0;
}

__global__ void k_count(const void* __restrict__ ei, int E, const int* __restrict__ flag,
                        int* __restrict__ counts) {
  int e = blockIdx.x * blockDim.x + threadIdx.x;
  if (e < E) {
    int d = load_ei(ei, (long long)E + e, *flag);
    atomicAdd(&counts[d], 1);
  }
}

// Single-block scan: row_ptr (exclusive prefix of counts) and dis = rsqrt(deg+1)
__global__ __launch_bounds__(1024) void k_scan(const int* __restrict__ counts,
                                               int* __restrict__ row_ptr,
                                               float* __restrict__ dis, int N) {
  __shared__ int ssum[1024];
  __shared__ int s_carry;
  int t = threadIdx.x;
  if (t == 0) { s_carry = 0; row_ptr[0] = 0; }
  __syncthreads();
  for (int base = 0; base < N; base += 8192) {
    int vals[8];
    int i0 = base + t * 8;
    int local = 0;
#pragma unroll
    for (int j = 0; j < 8; ++j) {
      int i = i0 + j;
      int v = (i < N) ? counts[i] : 0;
      vals[j] = v;
      local += v;
    }
    ssum[t] = local;
    __syncthreads();
    for (int s = 1; s < 1024; s <<= 1) {
      int tmp = (t >= s) ? ssum[t - s] : 0;
      __syncthreads();
      ssum[t] += tmp;
      __syncthreads();
    }
    int run = s_carry + ((t > 0) ? ssum[t - 1] : 0);
#pragma unroll
    for (int j = 0; j < 8; ++j) {
      int i = i0 + j;
      run += vals[j];
      if (i < N) {
        row_ptr[i + 1] = run;
        dis[i] = rsqrtf((float)(vals[j] + 1));  // +1 self-loop; always > 0
      }
    }
    __syncthreads();
    if (t == 1023) s_carry += ssum[1023];
    __syncthreads();
  }
}

__global__ void k_fill(const void* __restrict__ ei, int E, const int* __restrict__ flag,
                       const int* __restrict__ row_ptr, int* __restrict__ cursor,
                       int* __restrict__ edge_src) {
  int e = blockIdx.x * blockDim.x + threadIdx.x;
  if (e < E) {
    int is64 = *flag;
    int s = load_ei(ei, e, is64);
    int d = load_ei(ei, (long long)E + e, is64);
    int pos = row_ptr[d] + atomicAdd(&cursor[d], 1);
    edge_src[pos] = s;
  }
}

// g[i,:] = dis[i] * (x[i,:] @ W). Block = 256 threads, 32 rows/block.
// W (128x128 f32 = 64 KB) + transposed x tile (128k x 32row = 16 KB) in LDS.
__global__ __launch_bounds__(256) void k_gemm(const float* __restrict__ x,
                                              const float* __restrict__ W,
                                              const float* __restrict__ dis,
                                              float* __restrict__ g, int N) {
  __shared__ float Ws[NCH * NCH];
  __shared__ float xsT[NCH * GR];  // [k][row]
  int t = threadIdx.x;

  // Stage W: 4096 float4 / 256 threads = 16 each, coalesced.
  {
    float4* Wv = (float4*)Ws;
    const float4* Wg = (const float4*)W;
#pragma unroll
    for (int j = 0; j < 16; ++j) Wv[t + 256 * j] = Wg[t + 256 * j];
  }

  int row0 = blockIdx.x * GR;
  // Stage x tile transposed: thread loads row r = t>>3, k-range (t&7)*16..+16
  {
    int r = t >> 3;
    int k0 = (t & 7) * 16;
    int row = row0 + r;
    float4 a[4];
    if (row < N) {
      const float4* xg = (const float4*)(x + (long long)row * NCH + k0);
#pragma unroll
      for (int j = 0; j < 4; ++j) a[j] = xg[j];
    } else {
#pragma unroll
      for (int j = 0; j < 4; ++j) a[j] = make_float4(0.f, 0.f, 0.f, 0.f);
    }
    const float* af = (const float*)a;
#pragma unroll
    for (int j = 0; j < 16; ++j) xsT[(k0 + j) * GR + r] = af[j];
  }
  __syncthreads();

  int c = t & 127;
  int half = t >> 7;  // 0 or 1 -> rows half*16..half*16+15
  float acc[16];
#pragma unroll
  for (int r = 0; r < 16; ++r) acc[r] = 0.f;

#pragma unroll 4
  for (int k = 0; k < NCH; ++k) {
    float w = Ws[k * NCH + c];
    const float4* xv = (const float4*)(&xsT[k * GR + half * 16]);
    float4 a0 = xv[0], a1 = xv[1], a2 = xv[2], a3 = xv[3];
    acc[0]  = fmaf(a0.x, w, acc[0]);
    acc[1]  = fmaf(a0.y, w, acc[1]);
    acc[2]  = fmaf(a0.z, w, acc[2]);
    acc[3]  = fmaf(a0.w, w, acc[3]);
    acc[4]  = fmaf(a1.x, w, acc[4]);
    acc[5]  = fmaf(a1.y, w, acc[5]);
    acc[6]  = fmaf(a1.z, w, acc[6]);
    acc[7]  = fmaf(a1.w, w, acc[7]);
    acc[8]  = fmaf(a2.x, w, acc[8]);
    acc[9]  = fmaf(a2.y, w, acc[9]);
    acc[10] = fmaf(a2.z, w, acc[10]);
    acc[11] = fmaf(a2.w, w, acc[11]);
    acc[12] = fmaf(a3.x, w, acc[12]);
    acc[13] = fmaf(a3.y, w, acc[13]);
    acc[14] = fmaf(a3.z, w, acc[14]);
    acc[15] = fmaf(a3.w, w, acc[15]);
  }

  int rbase = row0 + half * 16;
#pragma unroll
  for (int r = 0; r < 16; ++r) {
    int row = rbase + r;
    if (row < N) g[(long long)row * NCH + c] = acc[r] * dis[row];
  }
}

// One wave per node; lane c owns channels [2c,2c+1]. 4 nodes per 256-thread block.
__global__ __launch_bounds__(256) void k_agg(const float* __restrict__ g,
                                             const int* __restrict__ row_ptr,
                                             const int* __restrict__ edge_src,
                                             const float* __restrict__ dis,
                                             const float* __restrict__ bias,
                                             float* __restrict__ out, int N) {
  int i = blockIdx.x * 4 + (threadIdx.x >> 6);
  if (i >= N) return;
  int c = threadIdx.x & 63;
  const float2* g2 = (const float2*)g;
  float2 acc = g2[(long long)i * 64 + c];  // self-loop term g[i]
  int e = row_ptr[i];
  int end = row_ptr[i + 1];
  for (; e + 4 <= end; e += 4) {
    int s0 = edge_src[e];
    int s1 = edge_src[e + 1];
    int s2 = edge_src[e + 2];
    int s3 = edge_src[e + 3];
    float2 v0 = g2[(long long)s0 * 64 + c];
    float2 v1 = g2[(long long)s1 * 64 + c];
    float2 v2 = g2[(long long)s2 * 64 + c];
    float2 v3 = g2[(long long)s3 * 64 + c];
    acc.x += (v0.x + v1.x) + (v2.x + v3.x);
    acc.y += (v0.y + v1.y) + (v2.y + v3.y);
  }
  for (; e < end; ++e) {
    int s = edge_src[e];
    float2 v = g2[(long long)s * 64 + c];
    acc.x += v.x;
    acc.y += v.y;
  }
  float di = dis[i];
  float2 bb = ((const float2*)bias)[c];
  float2 o;
  o.x = fmaxf(fmaf(acc.x, di, bb.x), 0.f);
  o.y = fmaxf(fmaf(acc.y, di, bb.y), 0.f);
  ((float2*)out)[(long long)i * 64 + c] = o;
}

extern "C" void kernel_launch(void* const* d_in, const int* in_sizes, int n_in,
                              void* d_out, int out_size, void* d_ws, size_t ws_size,
                              hipStream_t stream) {
  const float* x    = (const float*)d_in[0];
  const void*  ei   = d_in[1];
  const float* W    = (const float*)d_in[2];
  const float* bias = (const float*)d_in[3];
  float* out = (float*)d_out;

  int N = out_size / NCH;       // 50000
  int E = in_sizes[1] / 2;      // 800000

  char* ws = (char*)d_ws;
  size_t off = 0;
  auto alloc = [&](size_t bytes) -> char* {
    char* p = ws + off;
    off = (off + bytes + 255) & ~(size_t)255;
    return p;
  };
  int*   counts   = (int*)alloc((size_t)N * 4);
  int*   row_ptr  = (int*)alloc((size_t)(N + 1) * 4);
  int*   cursor   = (int*)alloc((size_t)N * 4);
  float* dis      = (float*)alloc((size_t)N * 4);
  int*   flag     = (int*)alloc(256);
  int*   edge_src = (int*)alloc((size_t)E * 4);
  float* g        = (float*)alloc((size_t)N * NCH * 4);
  (void)ws_size;

  hipMemsetAsync(counts, 0, (size_t)N * 4, stream);
  hipMemsetAsync(cursor, 0, (size_t)N * 4, stream);

  k_detect<<<1, 64, 0, stream>>>((const unsigned int*)ei, flag);
  k_count<<<(E + 255) / 256, 256, 0, stream>>>(ei, E, flag, counts);
  k_scan<<<1, 1024, 0, stream>>>(counts, row_ptr, dis, N);
  k_fill<<<(E + 255) / 256, 256, 0, stream>>>(ei, E, flag, row_ptr, cursor, edge_src);
  k_gemm<<<(N + GR - 1) / GR, 256, 0, stream>>>(x, W, dis, g, N);
  k_agg<<<(N + 3) / 4, 256, 0, stream>>>(g, row_ptr, edge_src, dis, bias, out, N);
}

// Round 2
// 278.684 us; speedup vs baseline: 1.2402x; 1.2402x over previous
//
#include <hip/hip_runtime.h>
#include <cstdint>
#include <cstddef>

#define NCH 128
#define GR 32
#define SCAN_CHUNK 2048  // 256 threads x 8 elems

__device__ __forceinline__ int load_ei(const void* p, long long i, int is64) {
  return is64 ? (int)((const long long*)p)[i] : ((const int*)p)[i];
}

// Detect whether edge_index is int64 (odd 32-bit words all zero) or int32.
__global__ void k_detect(const unsigned int* __restrict__ ei, int* __restrict__ flag) {
  int t = threadIdx.x;  // 0..63
  unsigned int v = ei[2 * t + 1];
  unsigned long long b = __ballot(v != 0u);
  if (t == 0) *flag = (b == 0ULL) ? 1 : 0;
}

__global__ void k_count(const void* __restrict__ ei, int E, const int* __restrict__ flag,
                        int* __restrict__ counts) {
  int e = blockIdx.x * blockDim.x + threadIdx.x;
  if (e < E) {
    int d = load_ei(ei, (long long)E + e, *flag);
    atomicAdd(&counts[d], 1);
  }
}

// ---- multi-block exclusive scan of counts -> row_ptr, plus dis & cursor ----

// Pass 1: per-block (2048-elem chunk) total.
__global__ __launch_bounds__(256) void k_scan1(const int* __restrict__ counts, int N,
                                               int* __restrict__ bsum) {
  int base = blockIdx.x * SCAN_CHUNK + threadIdx.x * 8;
  int s = 0;
  if (base + 8 <= N) {
    const int4* p = (const int4*)(counts + base);
    int4 a = p[0], b = p[1];
    s = (a.x + a.y) + (a.z + a.w) + (b.x + b.y) + (b.z + b.w);
  } else {
    for (int j = 0; j < 8; ++j) {
      int i = base + j;
      if (i < N) s += counts[i];
    }
  }
#pragma unroll
  for (int off = 32; off > 0; off >>= 1) s += __shfl_down(s, off);
  __shared__ int wsum[4];
  int w = threadIdx.x >> 6;
  if ((threadIdx.x & 63) == 0) wsum[w] = s;
  __syncthreads();
  if (threadIdx.x == 0) bsum[blockIdx.x] = (wsum[0] + wsum[1]) + (wsum[2] + wsum[3]);
}

// Pass 2: exclusive scan of block sums (nb small; single wave with carry loop).
__global__ void k_scan2(const int* __restrict__ bsum, int nb, int* __restrict__ boffs) {
  int lane = threadIdx.x;  // 64 threads
  int carry = 0;
  for (int base = 0; base < nb; base += 64) {
    int i = base + lane;
    int v = (i < nb) ? bsum[i] : 0;
    int incl = v;
#pragma unroll
    for (int off = 1; off < 64; off <<= 1) {
      int o = __shfl_up(incl, off);
      if (lane >= off) incl += o;
    }
    if (i < nb) boffs[i] = carry + incl - v;  // exclusive
    carry += __shfl(incl, 63);
  }
}

// Pass 3: local scan + block offset -> row_ptr[i+1]; also dis[i], cursor[i]=0.
__global__ __launch_bounds__(256) void k_scan3(const int* __restrict__ counts, int N,
                                               const int* __restrict__ boffs,
                                               int* __restrict__ row_ptr,
                                               float* __restrict__ dis,
                                               int* __restrict__ cursor) {
  int t = threadIdx.x;
  int base = blockIdx.x * SCAN_CHUNK + t * 8;
  int v[8];
  int s = 0;
  if (base + 8 <= N) {
    const int4* p = (const int4*)(counts + base);
    int4 a = p[0], b = p[1];
    v[0] = a.x; v[1] = a.y; v[2] = a.z; v[3] = a.w;
    v[4] = b.x; v[5] = b.y; v[6] = b.z; v[7] = b.w;
  } else {
#pragma unroll
    for (int j = 0; j < 8; ++j) {
      int i = base + j;
      v[j] = (i < N) ? counts[i] : 0;
    }
  }
#pragma unroll
  for (int j = 0; j < 8; ++j) s += v[j];

  int lane = t & 63, w = t >> 6;
  int incl = s;
#pragma unroll
  for (int off = 1; off < 64; off <<= 1) {
    int o = __shfl_up(incl, off);
    if (lane >= off) incl += o;
  }
  __shared__ int wsum[4];
  if (lane == 63) wsum[w] = incl;
  __syncthreads();
  int woff = 0;
#pragma unroll
  for (int k = 0; k < 4; ++k)
    if (k < w) woff += wsum[k];

  int run = boffs[blockIdx.x] + woff + (incl - s);  // exclusive prefix at base
#pragma unroll
  for (int j = 0; j < 8; ++j) {
    run += v[j];
    int i = base + j;
    if (i < N) {
      row_ptr[i + 1] = run;
      dis[i] = rsqrtf((float)(v[j] + 1));  // +1 self-loop; always > 0
      cursor[i] = 0;
    }
  }
  if (blockIdx.x == 0 && t == 0) row_ptr[0] = 0;
}

__global__ void k_fill(const void* __restrict__ ei, int E, const int* __restrict__ flag,
                       const int* __restrict__ row_ptr, int* __restrict__ cursor,
                       int* __restrict__ edge_src) {
  int e = blockIdx.x * blockDim.x + threadIdx.x;
  if (e < E) {
    int is64 = *flag;
    int s = load_ei(ei, e, is64);
    int d = load_ei(ei, (long long)E + e, is64);
    int pos = row_ptr[d] + atomicAdd(&cursor[d], 1);
    edge_src[pos] = s;
  }
}

// g[i,:] = dis[i] * (x[i,:] @ W). Block = 256 threads, 32 rows/block.
// W (128x128 f32 = 64 KB) + transposed x tile (128k x 32row = 16 KB) in LDS.
__global__ __launch_bounds__(256) void k_gemm(const float* __restrict__ x,
                                              const float* __restrict__ W,
                                              const float* __restrict__ dis,
                                              float* __restrict__ g, int N) {
  __shared__ float Ws[NCH * NCH];
  __shared__ float xsT[NCH * GR];  // [k][row]
  int t = threadIdx.x;

  {
    float4* Wv = (float4*)Ws;
    const float4* Wg = (const float4*)W;
#pragma unroll
    for (int j = 0; j < 16; ++j) Wv[t + 256 * j] = Wg[t + 256 * j];
  }

  int row0 = blockIdx.x * GR;
  {
    int r = t >> 3;
    int k0 = (t & 7) * 16;
    int row = row0 + r;
    float4 a[4];
    if (row < N) {
      const float4* xg = (const float4*)(x + (long long)row * NCH + k0);
#pragma unroll
      for (int j = 0; j < 4; ++j) a[j] = xg[j];
    } else {
#pragma unroll
      for (int j = 0; j < 4; ++j) a[j] = make_float4(0.f, 0.f, 0.f, 0.f);
    }
    const float* af = (const float*)a;
#pragma unroll
    for (int j = 0; j < 16; ++j) xsT[(k0 + j) * GR + r] = af[j];
  }
  __syncthreads();

  int c = t & 127;
  int half = t >> 7;
  float acc[16];
#pragma unroll
  for (int r = 0; r < 16; ++r) acc[r] = 0.f;

#pragma unroll 4
  for (int k = 0; k < NCH; ++k) {
    float w = Ws[k * NCH + c];
    const float4* xv = (const float4*)(&xsT[k * GR + half * 16]);
    float4 a0 = xv[0], a1 = xv[1], a2 = xv[2], a3 = xv[3];
    acc[0]  = fmaf(a0.x, w, acc[0]);
    acc[1]  = fmaf(a0.y, w, acc[1]);
    acc[2]  = fmaf(a0.z, w, acc[2]);
    acc[3]  = fmaf(a0.w, w, acc[3]);
    acc[4]  = fmaf(a1.x, w, acc[4]);
    acc[5]  = fmaf(a1.y, w, acc[5]);
    acc[6]  = fmaf(a1.z, w, acc[6]);
    acc[7]  = fmaf(a1.w, w, acc[7]);
    acc[8]  = fmaf(a2.x, w, acc[8]);
    acc[9]  = fmaf(a2.y, w, acc[9]);
    acc[10] = fmaf(a2.z, w, acc[10]);
    acc[11] = fmaf(a2.w, w, acc[11]);
    acc[12] = fmaf(a3.x, w, acc[12]);
    acc[13] = fmaf(a3.y, w, acc[13]);
    acc[14] = fmaf(a3.z, w, acc[14]);
    acc[15] = fmaf(a3.w, w, acc[15]);
  }

  int rbase = row0 + half * 16;
#pragma unroll
  for (int r = 0; r < 16; ++r) {
    int row = rbase + r;
    if (row < N) g[(long long)row * NCH + c] = acc[r] * dis[row];
  }
}

// One wave per node; lane c owns channels [2c,2c+1]. 4 nodes per 256-thread block.
__global__ __launch_bounds__(256) void k_agg(const float* __restrict__ g,
                                             const int* __restrict__ row_ptr,
                                             const int* __restrict__ edge_src,
                                             const float* __restrict__ dis,
                                             const float* __restrict__ bias,
                                             float* __restrict__ out, int N) {
  int i = blockIdx.x * 4 + (threadIdx.x >> 6);
  if (i >= N) return;
  int c = threadIdx.x & 63;
  const float2* g2 = (const float2*)g;
  float2 acc = g2[(long long)i * 64 + c];  // self-loop term g[i]
  int e = row_ptr[i];
  int end = row_ptr[i + 1];
  for (; e + 4 <= end; e += 4) {
    int s0 = edge_src[e];
    int s1 = edge_src[e + 1];
    int s2 = edge_src[e + 2];
    int s3 = edge_src[e + 3];
    float2 v0 = g2[(long long)s0 * 64 + c];
    float2 v1 = g2[(long long)s1 * 64 + c];
    float2 v2 = g2[(long long)s2 * 64 + c];
    float2 v3 = g2[(long long)s3 * 64 + c];
    acc.x += (v0.x + v1.x) + (v2.x + v3.x);
    acc.y += (v0.y + v1.y) + (v2.y + v3.y);
  }
  for (; e < end; ++e) {
    int s = edge_src[e];
    float2 v = g2[(long long)s * 64 + c];
    acc.x += v.x;
    acc.y += v.y;
  }
  float di = dis[i];
  float2 bb = ((const float2*)bias)[c];
  float2 o;
  o.x = fmaxf(fmaf(acc.x, di, bb.x), 0.f);
  o.y = fmaxf(fmaf(acc.y, di, bb.y), 0.f);
  ((float2*)out)[(long long)i * 64 + c] = o;
}

extern "C" void kernel_launch(void* const* d_in, const int* in_sizes, int n_in,
                              void* d_out, int out_size, void* d_ws, size_t ws_size,
                              hipStream_t stream) {
  const float* x    = (const float*)d_in[0];
  const void*  ei   = d_in[1];
  const float* W    = (const float*)d_in[2];
  const float* bias = (const float*)d_in[3];
  float* out = (float*)d_out;

  int N = out_size / NCH;       // 50000
  int E = in_sizes[1] / 2;      // 800000

  char* ws = (char*)d_ws;
  size_t off = 0;
  auto alloc = [&](size_t bytes) -> char* {
    char* p = ws + off;
    off = (off + bytes + 255) & ~(size_t)255;
    return p;
  };
  int*   counts   = (int*)alloc((size_t)N * 4);
  int*   row_ptr  = (int*)alloc((size_t)(N + 1) * 4);
  int*   cursor   = (int*)alloc((size_t)N * 4);
  float* dis      = (float*)alloc((size_t)N * 4);
  int*   flag     = (int*)alloc(256);
  int*   bsum     = (int*)alloc(4096);
  int*   boffs    = (int*)alloc(4096);
  int*   edge_src = (int*)alloc((size_t)E * 4);
  float* g        = (float*)alloc((size_t)N * NCH * 4);
  (void)ws_size;

  int nb = (N + SCAN_CHUNK - 1) / SCAN_CHUNK;

  hipMemsetAsync(counts, 0, (size_t)N * 4, stream);

  k_detect<<<1, 64, 0, stream>>>((const unsigned int*)ei, flag);
  k_count<<<(E + 255) / 256, 256, 0, stream>>>(ei, E, flag, counts);
  k_scan1<<<nb, 256, 0, stream>>>(counts, N, bsum);
  k_scan2<<<1, 64, 0, stream>>>(bsum, nb, boffs);
  k_scan3<<<nb, 256, 0, stream>>>(counts, N, boffs, row_ptr, dis, cursor);
  k_fill<<<(E + 255) / 256, 256, 0, stream>>>(ei, E, flag, row_ptr, cursor, edge_src);
  k_gemm<<<(N + GR - 1) / GR, 256, 0, stream>>>(x, W, dis, g, N);
  k_agg<<<(N + 3) / 4, 256, 0, stream>>>(g, row_ptr, edge_src, dis, bias, out, N);
}

// Round 3
// 220.775 us; speedup vs baseline: 1.5655x; 1.2623x over previous
//
#include <hip/hip_runtime.h>
#include <cstdint>
#include <cstddef>

#define NCH 128
#define GR 32
#define SCAN_CHUNK 2048  // 256 threads x 8 elems

__device__ __forceinline__ int load_ei(const void* p, long long i, int is64) {
  return is64 ? (int)((const long long*)p)[i] : ((const int*)p)[i];
}

// Inline int64-vs-int32 detection: for int64 edge_index with node ids < 2^31,
// all odd 32-bit words are zero. For int32, odd words are random node ids
// (P[all 64 zero] ~ (1/N)^64 ~ 0). Every wave computes the same answer.
// Must be called with all lanes of the wave active.
__device__ __forceinline__ int detect_is64(const unsigned int* __restrict__ ei) {
  unsigned int v = ei[((threadIdx.x & 63) << 1) + 1];
  return (__ballot(v != 0u) == 0ULL) ? 1 : 0;
}

// counts[d]++ per edge; rank[e] = this edge's arrival order at its destination.
__global__ __launch_bounds__(256) void k_count(const void* __restrict__ ei, int E,
                                               int* __restrict__ counts,
                                               int* __restrict__ rank) {
  int is64 = detect_is64((const unsigned int*)ei);
  int e = blockIdx.x * blockDim.x + threadIdx.x;
  if (e < E) {
    int d = load_ei(ei, (long long)E + e, is64);
    rank[e] = atomicAdd(&counts[d], 1);
  }
}

// Pass 1: per-block (2048-elem chunk) total of counts.
__global__ __launch_bounds__(256) void k_scan1(const int* __restrict__ counts, int N,
                                               int* __restrict__ bsum) {
  int base = blockIdx.x * SCAN_CHUNK + threadIdx.x * 8;
  int s = 0;
  if (base + 8 <= N) {
    const int4* p = (const int4*)(counts + base);
    int4 a = p[0], b = p[1];
    s = (a.x + a.y) + (a.z + a.w) + (b.x + b.y) + (b.z + b.w);
  } else {
    for (int j = 0; j < 8; ++j) {
      int i = base + j;
      if (i < N) s += counts[i];
    }
  }
#pragma unroll
  for (int off = 32; off > 0; off >>= 1) s += __shfl_down(s, off);
  __shared__ int wsum[4];
  int w = threadIdx.x >> 6;
  if ((threadIdx.x & 63) == 0) wsum[w] = s;
  __syncthreads();
  if (threadIdx.x == 0) bsum[blockIdx.x] = (wsum[0] + wsum[1]) + (wsum[2] + wsum[3]);
}

// Pass 2 (fused): each block wave-scans bsum to get its own offset, then does the
// local scan -> row_ptr[i+1], dis[i].
__global__ __launch_bounds__(256) void k_scan3(const int* __restrict__ counts, int N,
                                               int nb, const int* __restrict__ bsum,
                                               int* __restrict__ row_ptr,
                                               float* __restrict__ dis) {
  int t = threadIdx.x;
  __shared__ int s_boff;
  if (t < 64) {  // redundant per-block scan of the (<= a few dozen) block sums
    int carry = 0;
    for (int base = 0; base < nb; base += 64) {
      int i = base + t;
      int v = (i < nb) ? bsum[i] : 0;
      int inc = v;
#pragma unroll
      for (int off = 1; off < 64; off <<= 1) {
        int o = __shfl_up(inc, off);
        if (t >= off) inc += o;
      }
      if (i == (int)blockIdx.x) s_boff = carry + inc - v;  // exclusive prefix
      carry += __shfl(inc, 63);
    }
  }

  int base = blockIdx.x * SCAN_CHUNK + t * 8;
  int v[8];
  int s = 0;
  if (base + 8 <= N) {
    const int4* p = (const int4*)(counts + base);
    int4 a = p[0], b = p[1];
    v[0] = a.x; v[1] = a.y; v[2] = a.z; v[3] = a.w;
    v[4] = b.x; v[5] = b.y; v[6] = b.z; v[7] = b.w;
  } else {
#pragma unroll
    for (int j = 0; j < 8; ++j) {
      int i = base + j;
      v[j] = (i < N) ? counts[i] : 0;
    }
  }
#pragma unroll
  for (int j = 0; j < 8; ++j) s += v[j];

  int lane = t & 63, w = t >> 6;
  int incl = s;
#pragma unroll
  for (int off = 1; off < 64; off <<= 1) {
    int o = __shfl_up(incl, off);
    if (lane >= off) incl += o;
  }
  __shared__ int wsum[4];
  if (lane == 63) wsum[w] = incl;
  __syncthreads();
  int woff = 0;
#pragma unroll
  for (int k = 0; k < 4; ++k)
    if (k < w) woff += wsum[k];

  int run = s_boff + woff + (incl - s);  // exclusive prefix at base
#pragma unroll
  for (int j = 0; j < 8; ++j) {
    run += v[j];
    int i = base + j;
    if (i < N) {
      row_ptr[i + 1] = run;
      dis[i] = rsqrtf((float)(v[j] + 1));  // +1 self-loop; always > 0
    }
  }
  if (blockIdx.x == 0 && t == 0) row_ptr[0] = 0;
}

// CSR fill without atomics: pos = row_ptr[d] + rank[e].
__global__ __launch_bounds__(256) void k_fill(const void* __restrict__ ei, int E,
                                              const int* __restrict__ rank,
                                              const int* __restrict__ row_ptr,
                                              int* __restrict__ edge_src) {
  int is64 = detect_is64((const unsigned int*)ei);
  int e = blockIdx.x * blockDim.x + threadIdx.x;
  if (e < E) {
    int s = load_ei(ei, e, is64);
    int d = load_ei(ei, (long long)E + e, is64);
    edge_src[row_ptr[d] + rank[e]] = s;
  }
}

__device__ __forceinline__ unsigned short f2bf(float x) {
  unsigned int u = __float_as_uint(x);
  u += 0x7fffu + ((u >> 16) & 1u);  // RNE
  return (unsigned short)(u >> 16);
}

// g[i,:] = bf16( dis[i] * (x[i,:] @ W) ). Block = 256 threads, 32 rows/block.
__global__ __launch_bounds__(256) void k_gemm(const float* __restrict__ x,
                                              const float* __restrict__ W,
                                              const float* __restrict__ dis,
                                              unsigned short* __restrict__ g, int N) {
  __shared__ float Ws[NCH * NCH];
  __shared__ float xsT[NCH * GR];  // [k][row]
  int t = threadIdx.x;

  {
    float4* Wv = (float4*)Ws;
    const float4* Wg = (const float4*)W;
#pragma unroll
    for (int j = 0; j < 16; ++j) Wv[t + 256 * j] = Wg[t + 256 * j];
  }

  int row0 = blockIdx.x * GR;
  {
    int r = t >> 3;
    int k0 = (t & 7) * 16;
    int row = row0 + r;
    float4 a[4];
    if (row < N) {
      const float4* xg = (const float4*)(x + (long long)row * NCH + k0);
#pragma unroll
      for (int j = 0; j < 4; ++j) a[j] = xg[j];
    } else {
#pragma unroll
      for (int j = 0; j < 4; ++j) a[j] = make_float4(0.f, 0.f, 0.f, 0.f);
    }
    const float* af = (const float*)a;
#pragma unroll
    for (int j = 0; j < 16; ++j) xsT[(k0 + j) * GR + r] = af[j];
  }
  __syncthreads();

  int c = t & 127;
  int half = t >> 7;
  float acc[16];
#pragma unroll
  for (int r = 0; r < 16; ++r) acc[r] = 0.f;

#pragma unroll 4
  for (int k = 0; k < NCH; ++k) {
    float w = Ws[k * NCH + c];
    const float4* xv = (const float4*)(&xsT[k * GR + half * 16]);
    float4 a0 = xv[0], a1 = xv[1], a2 = xv[2], a3 = xv[3];
    acc[0]  = fmaf(a0.x, w, acc[0]);
    acc[1]  = fmaf(a0.y, w, acc[1]);
    acc[2]  = fmaf(a0.z, w, acc[2]);
    acc[3]  = fmaf(a0.w, w, acc[3]);
    acc[4]  = fmaf(a1.x, w, acc[4]);
    acc[5]  = fmaf(a1.y, w, acc[5]);
    acc[6]  = fmaf(a1.z, w, acc[6]);
    acc[7]  = fmaf(a1.w, w, acc[7]);
    acc[8]  = fmaf(a2.x, w, acc[8]);
    acc[9]  = fmaf(a2.y, w, acc[9]);
    acc[10] = fmaf(a2.z, w, acc[10]);
    acc[11] = fmaf(a2.w, w, acc[11]);
    acc[12] = fmaf(a3.x, w, acc[12]);
    acc[13] = fmaf(a3.y, w, acc[13]);
    acc[14] = fmaf(a3.z, w, acc[14]);
    acc[15] = fmaf(a3.w, w, acc[15]);
  }

  int rbase = row0 + half * 16;
#pragma unroll
  for (int r = 0; r < 16; ++r) {
    int row = rbase + r;
    if (row < N) g[(long long)row * NCH + c] = f2bf(acc[r] * dis[row]);
  }
}

// One wave per node; lane c owns channels [2c,2c+1] packed in one u32 (2x bf16).
__global__ __launch_bounds__(256) void k_agg(const unsigned int* __restrict__ gbits,
                                             const int* __restrict__ row_ptr,
                                             const int* __restrict__ edge_src,
                                             const float* __restrict__ dis,
                                             const float* __restrict__ bias,
                                             float* __restrict__ out, int N) {
  int i = blockIdx.x * 4 + (threadIdx.x >> 6);
  if (i >= N) return;
  int c = threadIdx.x & 63;
  unsigned int vi = gbits[(long long)i * 64 + c];  // self-loop term
  float ax = __uint_as_float(vi << 16);
  float ay = __uint_as_float(vi & 0xffff0000u);
  int e = row_ptr[i];
  int end = row_ptr[i + 1];
  for (; e + 8 <= end; e += 8) {
    unsigned int v0 = gbits[(long long)edge_src[e]     * 64 + c];
    unsigned int v1 = gbits[(long long)edge_src[e + 1] * 64 + c];
    unsigned int v2 = gbits[(long long)edge_src[e + 2] * 64 + c];
    unsigned int v3 = gbits[(long long)edge_src[e + 3] * 64 + c];
    unsigned int v4 = gbits[(long long)edge_src[e + 4] * 64 + c];
    unsigned int v5 = gbits[(long long)edge_src[e + 5] * 64 + c];
    unsigned int v6 = gbits[(long long)edge_src[e + 6] * 64 + c];
    unsigned int v7 = gbits[(long long)edge_src[e + 7] * 64 + c];
    ax += ((__uint_as_float(v0 << 16) + __uint_as_float(v1 << 16)) +
           (__uint_as_float(v2 << 16) + __uint_as_float(v3 << 16))) +
          ((__uint_as_float(v4 << 16) + __uint_as_float(v5 << 16)) +
           (__uint_as_float(v6 << 16) + __uint_as_float(v7 << 16)));
    ay += ((__uint_as_float(v0 & 0xffff0000u) + __uint_as_float(v1 & 0xffff0000u)) +
           (__uint_as_float(v2 & 0xffff0000u) + __uint_as_float(v3 & 0xffff0000u))) +
          ((__uint_as_float(v4 & 0xffff0000u) + __uint_as_float(v5 & 0xffff0000u)) +
           (__uint_as_float(v6 & 0xffff0000u) + __uint_as_float(v7 & 0xffff0000u)));
  }
  for (; e < end; ++e) {
    unsigned int v = gbits[(long long)edge_src[e] * 64 + c];
    ax += __uint_as_float(v << 16);
    ay += __uint_as_float(v & 0xffff0000u);
  }
  float di = dis[i];
  float2 bb = ((const float2*)bias)[c];
  float2 o;
  o.x = fmaxf(fmaf(ax, di, bb.x), 0.f);
  o.y = fmaxf(fmaf(ay, di, bb.y), 0.f);
  ((float2*)out)[(long long)i * 64 + c] = o;
}

extern "C" void kernel_launch(void* const* d_in, const int* in_sizes, int n_in,
                              void* d_out, int out_size, void* d_ws, size_t ws_size,
                              hipStream_t stream) {
  const float* x    = (const float*)d_in[0];
  const void*  ei   = d_in[1];
  const float* W    = (const float*)d_in[2];
  const float* bias = (const float*)d_in[3];
  float* out = (float*)d_out;

  int N = out_size / NCH;       // 50000
  int E = in_sizes[1] / 2;      // 800000

  char* ws = (char*)d_ws;
  size_t off = 0;
  auto alloc = [&](size_t bytes) -> char* {
    char* p = ws + off;
    off = (off + bytes + 255) & ~(size_t)255;
    return p;
  };
  int*            counts   = (int*)alloc((size_t)N * 4);
  int*            row_ptr  = (int*)alloc((size_t)(N + 1) * 4);
  float*          dis      = (float*)alloc((size_t)N * 4);
  int*            bsum     = (int*)alloc(4096);
  int*            rank     = (int*)alloc((size_t)E * 4);
  int*            edge_src = (int*)alloc((size_t)E * 4);
  unsigned short* g        = (unsigned short*)alloc((size_t)N * NCH * 2);
  (void)ws_size;

  int nb = (N + SCAN_CHUNK - 1) / SCAN_CHUNK;

  hipMemsetAsync(counts, 0, (size_t)N * 4, stream);

  k_count<<<(E + 255) / 256, 256, 0, stream>>>(ei, E, counts, rank);
  k_scan1<<<nb, 256, 0, stream>>>(counts, N, bsum);
  k_scan3<<<nb, 256, 0, stream>>>(counts, N, nb, bsum, row_ptr, dis);
  k_fill<<<(E + 255) / 256, 256, 0, stream>>>(ei, E, rank, row_ptr, edge_src);
  k_gemm<<<(N + GR - 1) / GR, 256, 0, stream>>>(x, W, dis, g, N);
  k_agg<<<(N + 3) / 4, 256, 0, stream>>>((const unsigned int*)g, row_ptr, edge_src,
                                         dis, bias, out, N);
}

// Round 4
// 186.180 us; speedup vs baseline: 1.8564x; 1.1858x over previous
//
#include <hip/hip_runtime.h>
#include <cstdint>
#include <cstddef>

#define NCH 128
#define SCAN_CHUNK 2048  // 256 threads x 8 elems
#define GEMM_ROWS 64
#define XPAD 136         // 128 + 8 bf16 pad: A-frag ds_read_b128 is conflict-free

typedef short bf16x8 __attribute__((ext_vector_type(8)));
typedef float f32x4 __attribute__((ext_vector_type(4)));

__device__ __forceinline__ int load_ei(const void* p, long long i, int is64) {
  return is64 ? (int)((const long long*)p)[i] : ((const int*)p)[i];
}

// Inline int64-vs-int32 detection: for int64 edge_index with ids < 2^31 all odd
// 32-bit words are zero; for int32 they are random node ids. Wave-uniform.
__device__ __forceinline__ int detect_is64(const unsigned int* __restrict__ ei) {
  unsigned int v = ei[((threadIdx.x & 63) << 1) + 1];
  return (__ballot(v != 0u) == 0ULL) ? 1 : 0;
}

__device__ __forceinline__ unsigned short f2bf(float x) {
  unsigned int u = __float_as_uint(x);
  u += 0x7fffu + ((u >> 16) & 1u);  // RNE
  return (unsigned short)(u >> 16);
}

// counts[d]++ per edge; rank[e] = this edge's arrival order at its destination.
__global__ __launch_bounds__(256) void k_count(const void* __restrict__ ei, int E,
                                               int* __restrict__ counts,
                                               int* __restrict__ rank) {
  int is64 = detect_is64((const unsigned int*)ei);
  int e = blockIdx.x * blockDim.x + threadIdx.x;
  if (e < E) {
    int d = load_ei(ei, (long long)E + e, is64);
    rank[e] = atomicAdd(&counts[d], 1);
  }
}

// Pass 1: per-block chunk total of counts. Blocks >= nb instead transpose W
// into bf16 Wt[n][k] (one-time 32 KB table for the MFMA B operand).
__global__ __launch_bounds__(256) void k_scan1(const int* __restrict__ counts, int N,
                                               int nb, int* __restrict__ bsum,
                                               const float* __restrict__ W,
                                               unsigned short* __restrict__ wt) {
  if ((int)blockIdx.x >= nb) {
    int idx = (blockIdx.x - nb) * 256 + threadIdx.x;  // 0..16383
    int n = idx >> 7, k = idx & 127;
    wt[idx] = f2bf(W[k * NCH + n]);
    return;
  }
  int base = blockIdx.x * SCAN_CHUNK + threadIdx.x * 8;
  int s = 0;
  if (base + 8 <= N) {
    const int4* p = (const int4*)(counts + base);
    int4 a = p[0], b = p[1];
    s = (a.x + a.y) + (a.z + a.w) + (b.x + b.y) + (b.z + b.w);
  } else {
    for (int j = 0; j < 8; ++j) {
      int i = base + j;
      if (i < N) s += counts[i];
    }
  }
#pragma unroll
  for (int off = 32; off > 0; off >>= 1) s += __shfl_down(s, off);
  __shared__ int wsum[4];
  int w = threadIdx.x >> 6;
  if ((threadIdx.x & 63) == 0) wsum[w] = s;
  __syncthreads();
  if (threadIdx.x == 0) bsum[blockIdx.x] = (wsum[0] + wsum[1]) + (wsum[2] + wsum[3]);
}

// Pass 2 (fused): each block wave-scans bsum for its own offset, then local scan
// -> row_ptr[i+1], dis[i].
__global__ __launch_bounds__(256) void k_scan3(const int* __restrict__ counts, int N,
                                               int nb, const int* __restrict__ bsum,
                                               int* __restrict__ row_ptr,
                                               float* __restrict__ dis) {
  int t = threadIdx.x;
  __shared__ int s_boff;
  if (t < 64) {
    int carry = 0;
    for (int base = 0; base < nb; base += 64) {
      int i = base + t;
      int v = (i < nb) ? bsum[i] : 0;
      int inc = v;
#pragma unroll
      for (int off = 1; off < 64; off <<= 1) {
        int o = __shfl_up(inc, off);
        if (t >= off) inc += o;
      }
      if (i == (int)blockIdx.x) s_boff = carry + inc - v;  // exclusive prefix
      carry += __shfl(inc, 63);
    }
  }

  int base = blockIdx.x * SCAN_CHUNK + t * 8;
  int v[8];
  int s = 0;
  if (base + 8 <= N) {
    const int4* p = (const int4*)(counts + base);
    int4 a = p[0], b = p[1];
    v[0] = a.x; v[1] = a.y; v[2] = a.z; v[3] = a.w;
    v[4] = b.x; v[5] = b.y; v[6] = b.z; v[7] = b.w;
  } else {
#pragma unroll
    for (int j = 0; j < 8; ++j) {
      int i = base + j;
      v[j] = (i < N) ? counts[i] : 0;
    }
  }
#pragma unroll
  for (int j = 0; j < 8; ++j) s += v[j];

  int lane = t & 63, w = t >> 6;
  int incl = s;
#pragma unroll
  for (int off = 1; off < 64; off <<= 1) {
    int o = __shfl_up(incl, off);
    if (lane >= off) incl += o;
  }
  __shared__ int wsum[4];
  if (lane == 63) wsum[w] = incl;
  __syncthreads();
  int woff = 0;
#pragma unroll
  for (int k = 0; k < 4; ++k)
    if (k < w) woff += wsum[k];

  int run = s_boff + woff + (incl - s);
#pragma unroll
  for (int j = 0; j < 8; ++j) {
    run += v[j];
    int i = base + j;
    if (i < N) {
      row_ptr[i + 1] = run;
      dis[i] = rsqrtf((float)(v[j] + 1));  // +1 self-loop; always > 0
    }
  }
  if (blockIdx.x == 0 && t == 0) row_ptr[0] = 0;
}

// CSR fill without atomics: pos = row_ptr[d] + rank[e].
__global__ __launch_bounds__(256) void k_fill(const void* __restrict__ ei, int E,
                                              const int* __restrict__ rank,
                                              const int* __restrict__ row_ptr,
                                              int* __restrict__ edge_src) {
  int is64 = detect_is64((const unsigned int*)ei);
  int e = blockIdx.x * blockDim.x + threadIdx.x;
  if (e < E) {
    int s = load_ei(ei, e, is64);
    int d = load_ei(ei, (long long)E + e, is64);
    edge_src[row_ptr[d] + rank[e]] = s;
  }
}

// MFMA GEMM: g[i,:] = bf16( dis[i] * (x[i,:] @ W) ).
// 64 rows/block, 4 waves; wave w -> output cols [32w, 32w+32).
// Shape 16x16x32 bf16: A[m=lane&15][k=(lane>>4)*8+j], B[k][n=lane&15] same k map,
// C/D: col=lane&15, row=(lane>>4)*4+reg  (all HW-verified mappings).
__global__ __launch_bounds__(256) void k_gemm(const float* __restrict__ x,
                                              const unsigned short* __restrict__ wt,
                                              const float* __restrict__ dis,
                                              unsigned short* __restrict__ g, int N) {
  __shared__ unsigned short xbf[GEMM_ROWS * XPAD];
  __shared__ float sdis[GEMM_ROWS];
  int t = threadIdx.x;
  int row0 = blockIdx.x * GEMM_ROWS;

  // Stage x tile -> bf16 LDS. 2048 float4 loads over 8 iters, coalesced.
#pragma unroll
  for (int j = 0; j < 8; ++j) {
    int idx = t + 256 * j;      // 0..2047
    int r = idx >> 5;           // row 0..63
    int ch = idx & 31;          // float4 chunk
    int row = row0 + r;
    float4 v = (row < N) ? ((const float4*)(x + (size_t)row * NCH))[ch]
                         : make_float4(0.f, 0.f, 0.f, 0.f);
    ushort4 p;
    p.x = f2bf(v.x); p.y = f2bf(v.y); p.z = f2bf(v.z); p.w = f2bf(v.w);
    *(ushort4*)&xbf[r * XPAD + ch * 4] = p;
  }
  if (t < GEMM_ROWS) {
    int row = row0 + t;
    sdis[t] = (row < N) ? dis[row] : 0.f;
  }

  int lane = t & 63;
  int wv = t >> 6;
  int n0 = wv * 32;
  int l15 = lane & 15;
  int q = lane >> 4;  // 0..3

  // Preload B: 8 frags (ks 0..3  x  nt 0..1), 16-B aligned loads from Wt (L2-hot).
  bf16x8 B[4][2];
#pragma unroll
  for (int ks = 0; ks < 4; ++ks)
#pragma unroll
    for (int nt = 0; nt < 2; ++nt) {
      int n = n0 + nt * 16 + l15;
      B[ks][nt] = *(const bf16x8*)(wt + (size_t)n * NCH + ks * 32 + q * 8);
    }

  __syncthreads();

  f32x4 acc[4][2];
#pragma unroll
  for (int mt = 0; mt < 4; ++mt)
#pragma unroll
    for (int nt = 0; nt < 2; ++nt)
#pragma unroll
      for (int i = 0; i < 4; ++i) acc[mt][nt][i] = 0.f;

#pragma unroll
  for (int ks = 0; ks < 4; ++ks) {
#pragma unroll
    for (int mt = 0; mt < 4; ++mt) {
      bf16x8 a = *(const bf16x8*)&xbf[(mt * 16 + l15) * XPAD + ks * 32 + q * 8];
      acc[mt][0] = __builtin_amdgcn_mfma_f32_16x16x32_bf16(a, B[ks][0], acc[mt][0], 0, 0, 0);
      acc[mt][1] = __builtin_amdgcn_mfma_f32_16x16x32_bf16(a, B[ks][1], acc[mt][1], 0, 0, 0);
    }
  }

  // Epilogue: scale by dis[row], quantize, store.
#pragma unroll
  for (int mt = 0; mt < 4; ++mt) {
#pragma unroll
    for (int reg = 0; reg < 4; ++reg) {
      int rl = mt * 16 + q * 4 + reg;
      int row = row0 + rl;
      if (row < N) {
        float dl = sdis[rl];
        size_t base = (size_t)row * NCH + n0;
        g[base + l15]      = f2bf(acc[mt][0][reg] * dl);
        g[base + 16 + l15] = f2bf(acc[mt][1][reg] * dl);
      }
    }
  }
}

// One wave per node; lane c owns channels [2c,2c+1] packed in one u32 (2x bf16).
__global__ __launch_bounds__(256) void k_agg(const unsigned int* __restrict__ gbits,
                                             const int* __restrict__ row_ptr,
                                             const int* __restrict__ edge_src,
                                             const float* __restrict__ dis,
                                             const float* __restrict__ bias,
                                             float* __restrict__ out, int N) {
  int i = blockIdx.x * 4 + (threadIdx.x >> 6);
  if (i >= N) return;
  int c = threadIdx.x & 63;
  unsigned int vi = gbits[(long long)i * 64 + c];  // self-loop term
  float ax = __uint_as_float(vi << 16);
  float ay = __uint_as_float(vi & 0xffff0000u);
  int e = row_ptr[i];
  int end = row_ptr[i + 1];
  for (; e + 8 <= end; e += 8) {
    unsigned int v0 = gbits[(long long)edge_src[e]     * 64 + c];
    unsigned int v1 = gbits[(long long)edge_src[e + 1] * 64 + c];
    unsigned int v2 = gbits[(long long)edge_src[e + 2] * 64 + c];
    unsigned int v3 = gbits[(long long)edge_src[e + 3] * 64 + c];
    unsigned int v4 = gbits[(long long)edge_src[e + 4] * 64 + c];
    unsigned int v5 = gbits[(long long)edge_src[e + 5] * 64 + c];
    unsigned int v6 = gbits[(long long)edge_src[e + 6] * 64 + c];
    unsigned int v7 = gbits[(long long)edge_src[e + 7] * 64 + c];
    ax += ((__uint_as_float(v0 << 16) + __uint_as_float(v1 << 16)) +
           (__uint_as_float(v2 << 16) + __uint_as_float(v3 << 16))) +
          ((__uint_as_float(v4 << 16) + __uint_as_float(v5 << 16)) +
           (__uint_as_float(v6 << 16) + __uint_as_float(v7 << 16)));
    ay += ((__uint_as_float(v0 & 0xffff0000u) + __uint_as_float(v1 & 0xffff0000u)) +
           (__uint_as_float(v2 & 0xffff0000u) + __uint_as_float(v3 & 0xffff0000u))) +
          ((__uint_as_float(v4 & 0xffff0000u) + __uint_as_float(v5 & 0xffff0000u)) +
           (__uint_as_float(v6 & 0xffff0000u) + __uint_as_float(v7 & 0xffff0000u)));
  }
  for (; e < end; ++e) {
    unsigned int v = gbits[(long long)edge_src[e] * 64 + c];
    ax += __uint_as_float(v << 16);
    ay += __uint_as_float(v & 0xffff0000u);
  }
  float di = dis[i];
  float2 bb = ((const float2*)bias)[c];
  float2 o;
  o.x = fmaxf(fmaf(ax, di, bb.x), 0.f);
  o.y = fmaxf(fmaf(ay, di, bb.y), 0.f);
  ((float2*)out)[(long long)i * 64 + c] = o;
}

extern "C" void kernel_launch(void* const* d_in, const int* in_sizes, int n_in,
                              void* d_out, int out_size, void* d_ws, size_t ws_size,
                              hipStream_t stream) {
  const float* x    = (const float*)d_in[0];
  const void*  ei   = d_in[1];
  const float* W    = (const float*)d_in[2];
  const float* bias = (const float*)d_in[3];
  float* out = (float*)d_out;

  int N = out_size / NCH;       // 50000
  int E = in_sizes[1] / 2;      // 800000

  char* ws = (char*)d_ws;
  size_t off = 0;
  auto alloc = [&](size_t bytes) -> char* {
    char* p = ws + off;
    off = (off + bytes + 255) & ~(size_t)255;
    return p;
  };
  int*            counts   = (int*)alloc((size_t)N * 4);
  int*            row_ptr  = (int*)alloc((size_t)(N + 1) * 4);
  float*          dis      = (float*)alloc((size_t)N * 4);
  int*            bsum     = (int*)alloc(4096);
  unsigned short* wt       = (unsigned short*)alloc((size_t)NCH * NCH * 2);
  int*            rank     = (int*)alloc((size_t)E * 4);
  int*            edge_src = (int*)alloc((size_t)E * 4);
  unsigned short* g        = (unsigned short*)alloc((size_t)N * NCH * 2);
  (void)ws_size;

  int nb = (N + SCAN_CHUNK - 1) / SCAN_CHUNK;

  hipMemsetAsync(counts, 0, (size_t)N * 4, stream);

  k_count<<<(E + 255) / 256, 256, 0, stream>>>(ei, E, counts, rank);
  k_scan1<<<nb + 64, 256, 0, stream>>>(counts, N, nb, bsum, W, wt);
  k_scan3<<<nb, 256, 0, stream>>>(counts, N, nb, bsum, row_ptr, dis);
  k_fill<<<(E + 255) / 256, 256, 0, stream>>>(ei, E, rank, row_ptr, edge_src);
  k_gemm<<<(N + GEMM_ROWS - 1) / GEMM_ROWS, 256, 0, stream>>>(x, wt, dis, g, N);
  k_agg<<<(N + 3) / 4, 256, 0, stream>>>((const unsigned int*)g, row_ptr, edge_src,
                                         dis, bias, out, N);
}

// Round 6
// 186.050 us; speedup vs baseline: 1.8577x; 1.0007x over previous
//
#include <hip/hip_runtime.h>
#include <cstdint>
#include <cstddef>

#define NCH 128
#define SCAN_CHUNK 2048  // 256 threads x 8 elems
#define GEMM_ROWS 64
#define XPAD 136         // 128 + 8 bf16 pad: A-frag ds_read_b128 is conflict-free

typedef short bf16x8 __attribute__((ext_vector_type(8)));
typedef float f32x4 __attribute__((ext_vector_type(4)));

__device__ __forceinline__ int load_ei(const void* p, long long i, int is64) {
  return is64 ? (int)((const long long*)p)[i] : ((const int*)p)[i];
}

// Inline int64-vs-int32 detection: for int64 edge_index with ids < 2^31 all odd
// 32-bit words are zero; for int32 they are random node ids. Wave-uniform.
// Call with all lanes of the wave active.
__device__ __forceinline__ int detect_is64(const unsigned int* __restrict__ ei) {
  unsigned int v = ei[((threadIdx.x & 63) << 1) + 1];
  return (__ballot(v != 0u) == 0ULL) ? 1 : 0;
}

__device__ __forceinline__ unsigned short f2bf(float x) {
  unsigned int u = __float_as_uint(x);
  u += 0x7fffu + ((u >> 16) & 1u);  // RNE
  return (unsigned short)(u >> 16);
}

// counts[d]++ per edge (2 edges/thread); rank[e] = arrival order at destination.
// Blocks >= ebl instead transpose W into bf16 Wt[n][k] (MFMA B operand).
__global__ __launch_bounds__(256) void k_count(const void* __restrict__ ei, int E,
                                               int ebl, int* __restrict__ counts,
                                               int* __restrict__ rank,
                                               const float* __restrict__ W,
                                               unsigned short* __restrict__ wt) {
  if ((int)blockIdx.x >= ebl) {
    int idx = (blockIdx.x - ebl) * 256 + threadIdx.x;  // 0..16383
    int n = idx >> 7, k = idx & 127;
    wt[idx] = f2bf(W[k * NCH + n]);
    return;
  }
  int is64 = detect_is64((const unsigned int*)ei);
  int e0 = (blockIdx.x * 256 + threadIdx.x) * 2;
  if (e0 >= E) return;
  bool two = (e0 + 1 < E);
  int d0, d1 = 0;
  if (is64) {
    const long long* q = (const long long*)ei + E + e0;
    d0 = (int)q[0];
    if (two) d1 = (int)q[1];
  } else {
    const int* q = (const int*)ei + E + e0;
    d0 = q[0];
    if (two) d1 = q[1];
  }
  rank[e0] = atomicAdd(&counts[d0], 1);
  if (two) rank[e0 + 1] = atomicAdd(&counts[d1], 1);
}

// Single-pass exclusive scan (decoupled lookback, nb<=64 blocks co-resident on
// 256 CUs): row_ptr[i+1] = prefix, dis[i] = rsqrt(deg+1). flagsum[b] u64 =
// (1<<63) | block_total, published with agent-scope release.
__global__ __launch_bounds__(256) void k_scan(const int* __restrict__ counts, int N,
                                              unsigned long long* __restrict__ flagsum,
                                              int* __restrict__ row_ptr,
                                              float* __restrict__ dis) {
  int t = threadIdx.x;
  int base = blockIdx.x * SCAN_CHUNK + t * 8;
  int v[8];
  int s = 0;
  if (base + 8 <= N) {
    const int4* p = (const int4*)(counts + base);
    int4 a = p[0], b = p[1];
    v[0] = a.x; v[1] = a.y; v[2] = a.z; v[3] = a.w;
    v[4] = b.x; v[5] = b.y; v[6] = b.z; v[7] = b.w;
  } else {
#pragma unroll
    for (int j = 0; j < 8; ++j) {
      int i = base + j;
      v[j] = (i < N) ? counts[i] : 0;
    }
  }
#pragma unroll
  for (int j = 0; j < 8; ++j) s += v[j];

  int lane = t & 63, w = t >> 6;
  int incl = s;
#pragma unroll
  for (int off = 1; off < 64; off <<= 1) {
    int o = __shfl_up(incl, off);
    if (lane >= off) incl += o;
  }
  __shared__ int wsum[4];
  __shared__ int s_boff;
  if (lane == 63) wsum[w] = incl;
  __syncthreads();

  if (t == 0) {
    int btot = (wsum[0] + wsum[1]) + (wsum[2] + wsum[3]);
    unsigned long long pub = (1ull << 63) | (unsigned int)btot;
    __hip_atomic_store(&flagsum[blockIdx.x], pub, __ATOMIC_RELEASE,
                       __HIP_MEMORY_SCOPE_AGENT);
    int acc = 0;
    for (int i = (int)blockIdx.x - 1; i >= 0; --i) {
      unsigned long long fv;
      do {
        fv = __hip_atomic_load(&flagsum[i], __ATOMIC_ACQUIRE,
                               __HIP_MEMORY_SCOPE_AGENT);
      } while (!(fv >> 63));
      acc += (int)(unsigned int)fv;
    }
    s_boff = acc;
  }
  __syncthreads();

  int woff = 0;
#pragma unroll
  for (int k = 0; k < 4; ++k)
    if (k < w) woff += wsum[k];

  int run = s_boff + woff + (incl - s);
#pragma unroll
  for (int j = 0; j < 8; ++j) {
    run += v[j];
    int i = base + j;
    if (i < N) {
      row_ptr[i + 1] = run;
      dis[i] = rsqrtf((float)(v[j] + 1));  // +1 self-loop; always > 0
    }
  }
  if (blockIdx.x == 0 && t == 0) row_ptr[0] = 0;
}

// CSR fill without atomics (2 edges/thread): pos = row_ptr[d] + rank[e].
__global__ __launch_bounds__(256) void k_fill(const void* __restrict__ ei, int E,
                                              const int* __restrict__ rank,
                                              const int* __restrict__ row_ptr,
                                              int* __restrict__ edge_src) {
  int is64 = detect_is64((const unsigned int*)ei);
  int e0 = (blockIdx.x * 256 + threadIdx.x) * 2;
  if (e0 >= E) return;
  bool two = (e0 + 1 < E);
  int s0, s1 = 0, d0, d1 = 0;
  if (is64) {
    const long long* qs = (const long long*)ei + e0;
    const long long* qd = (const long long*)ei + E + e0;
    s0 = (int)qs[0]; d0 = (int)qd[0];
    if (two) { s1 = (int)qs[1]; d1 = (int)qd[1]; }
  } else {
    const int* qs = (const int*)ei + e0;
    const int* qd = (const int*)ei + E + e0;
    s0 = qs[0]; d0 = qd[0];
    if (two) { s1 = qs[1]; d1 = qd[1]; }
  }
  edge_src[row_ptr[d0] + rank[e0]] = s0;
  if (two) edge_src[row_ptr[d1] + rank[e0 + 1]] = s1;
}

// MFMA GEMM: g[i,:] = bf16( dis[i] * (x[i,:] @ W) ).
// 64 rows/block, 4 waves; wave w -> output cols [32w, 32w+32).
__global__ __launch_bounds__(256) void k_gemm(const float* __restrict__ x,
                                              const unsigned short* __restrict__ wt,
                                              const float* __restrict__ dis,
                                              unsigned short* __restrict__ g, int N) {
  __shared__ unsigned short xbf[GEMM_ROWS * XPAD];
  __shared__ float sdis[GEMM_ROWS];
  int t = threadIdx.x;
  int row0 = blockIdx.x * GEMM_ROWS;

#pragma unroll
  for (int j = 0; j < 8; ++j) {
    int idx = t + 256 * j;      // 0..2047
    int r = idx >> 5;           // row 0..63
    int ch = idx & 31;          // float4 chunk
    int row = row0 + r;
    float4 v = (row < N) ? ((const float4*)(x + (size_t)row * NCH))[ch]
                         : make_float4(0.f, 0.f, 0.f, 0.f);
    ushort4 p;
    p.x = f2bf(v.x); p.y = f2bf(v.y); p.z = f2bf(v.z); p.w = f2bf(v.w);
    *(ushort4*)&xbf[r * XPAD + ch * 4] = p;
  }
  if (t < GEMM_ROWS) {
    int row = row0 + t;
    sdis[t] = (row < N) ? dis[row] : 0.f;
  }

  int lane = t & 63;
  int wv = t >> 6;
  int n0 = wv * 32;
  int l15 = lane & 15;
  int q = lane >> 4;  // 0..3

  bf16x8 B[4][2];
#pragma unroll
  for (int ks = 0; ks < 4; ++ks)
#pragma unroll
    for (int nt = 0; nt < 2; ++nt) {
      int n = n0 + nt * 16 + l15;
      B[ks][nt] = *(const bf16x8*)(wt + (size_t)n * NCH + ks * 32 + q * 8);
    }

  __syncthreads();

  f32x4 acc[4][2];
#pragma unroll
  for (int mt = 0; mt < 4; ++mt)
#pragma unroll
    for (int nt = 0; nt < 2; ++nt)
#pragma unroll
      for (int i = 0; i < 4; ++i) acc[mt][nt][i] = 0.f;

#pragma unroll
  for (int ks = 0; ks < 4; ++ks) {
#pragma unroll
    for (int mt = 0; mt < 4; ++mt) {
      bf16x8 a = *(const bf16x8*)&xbf[(mt * 16 + l15) * XPAD + ks * 32 + q * 8];
      acc[mt][0] = __builtin_amdgcn_mfma_f32_16x16x32_bf16(a, B[ks][0], acc[mt][0], 0, 0, 0);
      acc[mt][1] = __builtin_amdgcn_mfma_f32_16x16x32_bf16(a, B[ks][1], acc[mt][1], 0, 0, 0);
    }
  }

#pragma unroll
  for (int mt = 0; mt < 4; ++mt) {
#pragma unroll
    for (int reg = 0; reg < 4; ++reg) {
      int rl = mt * 16 + q * 4 + reg;
      int row = row0 + rl;
      if (row < N) {
        float dl = sdis[rl];
        size_t base = (size_t)row * NCH + n0;
        g[base + l15]      = f2bf(acc[mt][0][reg] * dl);
        g[base + 16 + l15] = f2bf(acc[mt][1][reg] * dl);
      }
    }
  }
}

// One wave per node, edge-pair loads: lane L -> half h=L>>5 (edge e+h), sublane
// sl=L&31 -> channels [4sl,4sl+4) as uint2 (4 bf16). Halves combined via
// shfl_xor(32); lanes h==0 write f32x4 output.
__global__ __launch_bounds__(256) void k_agg(const unsigned short* __restrict__ g,
                                             const int* __restrict__ row_ptr,
                                             const int* __restrict__ edge_src,
                                             const float* __restrict__ dis,
                                             const float* __restrict__ bias,
                                             float* __restrict__ out, int N) {
  int i = blockIdx.x * 4 + (threadIdx.x >> 6);
  if (i >= N) return;
  int lane = threadIdx.x & 63;
  int h = lane >> 5, sl = lane & 31;

  float a0 = 0.f, a1 = 0.f, a2 = 0.f, a3 = 0.f;
  // self-loop term: half 0 only
  if (h == 0) {
    uint2 v = *(const uint2*)(g + (size_t)i * NCH + sl * 4);
    a0 = __uint_as_float(v.x << 16);
    a1 = __uint_as_float(v.x & 0xffff0000u);
    a2 = __uint_as_float(v.y << 16);
    a3 = __uint_as_float(v.y & 0xffff0000u);
  }

  int e = row_ptr[i];
  int end = row_ptr[i + 1];
  for (; e + 8 <= end; e += 8) {
    int s0 = edge_src[e + h];
    int s1 = edge_src[e + 2 + h];
    int s2 = edge_src[e + 4 + h];
    int s3 = edge_src[e + 6 + h];
    uint2 v0 = *(const uint2*)(g + (size_t)s0 * NCH + sl * 4);
    uint2 v1 = *(const uint2*)(g + (size_t)s1 * NCH + sl * 4);
    uint2 v2 = *(const uint2*)(g + (size_t)s2 * NCH + sl * 4);
    uint2 v3 = *(const uint2*)(g + (size_t)s3 * NCH + sl * 4);
    a0 += (__uint_as_float(v0.x << 16) + __uint_as_float(v1.x << 16)) +
          (__uint_as_float(v2.x << 16) + __uint_as_float(v3.x << 16));
    a1 += (__uint_as_float(v0.x & 0xffff0000u) + __uint_as_float(v1.x & 0xffff0000u)) +
          (__uint_as_float(v2.x & 0xffff0000u) + __uint_as_float(v3.x & 0xffff0000u));
    a2 += (__uint_as_float(v0.y << 16) + __uint_as_float(v1.y << 16)) +
          (__uint_as_float(v2.y << 16) + __uint_as_float(v3.y << 16));
    a3 += (__uint_as_float(v0.y & 0xffff0000u) + __uint_as_float(v1.y & 0xffff0000u)) +
          (__uint_as_float(v2.y & 0xffff0000u) + __uint_as_float(v3.y & 0xffff0000u));
  }
  for (; e < end; e += 2) {
    int idx = e + h;
    if (idx < end) {
      uint2 v = *(const uint2*)(g + (size_t)edge_src[idx] * NCH + sl * 4);
      a0 += __uint_as_float(v.x << 16);
      a1 += __uint_as_float(v.x & 0xffff0000u);
      a2 += __uint_as_float(v.y << 16);
      a3 += __uint_as_float(v.y & 0xffff0000u);
    }
  }

  // combine halves
  a0 += __shfl_xor(a0, 32);
  a1 += __shfl_xor(a1, 32);
  a2 += __shfl_xor(a2, 32);
  a3 += __shfl_xor(a3, 32);

  if (h == 0) {
    float di = dis[i];
    float4 bb = ((const float4*)bias)[sl];
    f32x4 o;
    o[0] = fmaxf(fmaf(a0, di, bb.x), 0.f);
    o[1] = fmaxf(fmaf(a1, di, bb.y), 0.f);
    o[2] = fmaxf(fmaf(a2, di, bb.z), 0.f);
    o[3] = fmaxf(fmaf(a3, di, bb.w), 0.f);
    __builtin_nontemporal_store(o, (f32x4*)(out + (size_t)i * NCH + sl * 4));
  }
}

extern "C" void kernel_launch(void* const* d_in, const int* in_sizes, int n_in,
                              void* d_out, int out_size, void* d_ws, size_t ws_size,
                              hipStream_t stream) {
  const float* x    = (const float*)d_in[0];
  const void*  ei   = d_in[1];
  const float* W    = (const float*)d_in[2];
  const float* bias = (const float*)d_in[3];
  float* out = (float*)d_out;

  int N = out_size / NCH;       // 50000
  int E = in_sizes[1] / 2;      // 800000

  char* ws = (char*)d_ws;
  size_t off = 0;
  auto alloc = [&](size_t bytes) -> char* {
    char* p = ws + off;
    off = (off + bytes + 255) & ~(size_t)255;
    return p;
  };
  // zeroed region: counts + flagsum (one memset)
  char* zbase = ws;
  int*                counts  = (int*)alloc((size_t)N * 4);
  unsigned long long* flagsum = (unsigned long long*)alloc(1024);
  size_t zbytes = off;
  int*            row_ptr  = (int*)alloc((size_t)(N + 1) * 4);
  float*          dis      = (float*)alloc((size_t)N * 4);
  unsigned short* wt       = (unsigned short*)alloc((size_t)NCH * NCH * 2);
  int*            rank     = (int*)alloc((size_t)E * 4);
  int*            edge_src = (int*)alloc((size_t)E * 4);
  unsigned short* g        = (unsigned short*)alloc((size_t)N * NCH * 2);
  (void)ws_size;

  int nb = (N + SCAN_CHUNK - 1) / SCAN_CHUNK;          // 25
  int ebl = ((E + 1) / 2 + 255) / 256;                 // edge-pair blocks

  (void)hipMemsetAsync(zbase, 0, zbytes, stream);

  k_count<<<ebl + 64, 256, 0, stream>>>(ei, E, ebl, counts, rank, W, wt);
  k_scan<<<nb, 256, 0, stream>>>(counts, N, flagsum, row_ptr, dis);
  k_fill<<<ebl, 256, 0, stream>>>(ei, E, rank, row_ptr, edge_src);
  k_gemm<<<(N + GEMM_ROWS - 1) / GEMM_ROWS, 256, 0, stream>>>(x, wt, dis, g, N);
  k_agg<<<(N + 3) / 4, 256, 0, stream>>>(g, row_ptr, edge_src, dis, bias, out, N);
}